// Round 9
// baseline (2485.157 us; speedup 1.0000x reference)
//
#include <hip/hip_runtime.h>
#include <hip/hip_bf16.h>

// ByteLevelDecoder: B=2,S=256,H=1024, BH=384,NH=8,HD=48, P=4,S_C=12,L=4,V=258,T=16
// Persistent kernel, 1 block = 2 sequences, 768 threads = 12 waves/CU.
// Round 9: non-temporal hints on KV/x/Wproj/out traffic (keeps the recurring
// 3.54MB/visit weight stream L2-resident; FETCH showed ~half of weight reads
// missing to LLC); split-K epilogues split by sequence (both halves active).
// Gamma folded into Wq/Wk/Wv/W1; x^2 sums fused into GEMM epilogues.

constexpr int H_IN  = 1024;
constexpr int BH    = 384;
constexpr int NH    = 8;
constexpr int HD    = 48;
constexpr int PP    = 4;
constexpr int S_CNT = 12;
constexpr int NL    = 4;
constexpr int NV    = 258;
constexpr int TT    = 16;
constexpr int NSEQ  = 512;
constexpr int EOS_I = 257;
constexpr int NTH   = 768;
constexpr float RSCALE = 0.14433756729740646f;  // 1/sqrt(48)

typedef _Float16 h2 __attribute__((ext_vector_type(2)));
typedef _Float16 h8 __attribute__((ext_vector_type(8)));

union W16 { h8 v8; h2 h[4]; _Float16 e[8]; };

template<int N> struct IC { static constexpr int value = N; };

__device__ __forceinline__ float fdot2(h2 a, h2 b, float c) {
#if __has_builtin(__builtin_amdgcn_fdot2)
  return __builtin_amdgcn_fdot2(a, b, c, false);
#else
  return c + (float)a.x * (float)b.x + (float)a.y * (float)b.y;
#endif
}

template<typename T>
__device__ __forceinline__ T ntload(const T* p) { return __builtin_nontemporal_load(p); }
template<typename T>
__device__ __forceinline__ void ntstore(T* p, T v) { __builtin_nontemporal_store(v, p); }

// ---- repack prepass: dst[j8*C + c] = {g[8j8+r]*src[8*j8+r][c]}_{r=0..7} ----
__global__ __launch_bounds__(256)
void pack8_kernel(const float* __restrict__ src, const float* __restrict__ g,
                  h8* __restrict__ dst, int C) {
  int c  = blockIdx.x * 256 + threadIdx.x;
  int j8 = blockIdx.y;
  if (c < C) {
    h8 v;
    #pragma unroll
    for (int r = 0; r < 8; r++) {
      int row = 8 * j8 + r;
      float s = g ? g[row] : 1.0f;
      v[r] = (_Float16)(src[(size_t)row * C + c] * s);
    }
    dst[(size_t)j8 * C + c] = v;
  }
}

__global__ __launch_bounds__(NTH)
void decoder_kernel(const float* __restrict__ x,
                    const h8* __restrict__ Wproj8,   // [128][1536]
                    const h8* __restrict__ Wq8,      // [l*48][384], gamma-folded
                    const h8* __restrict__ Wk8,
                    const h8* __restrict__ Wv8,
                    const h8* __restrict__ Wo8,
                    const h8* __restrict__ W18,      // [l*48][1536], gamma-folded
                    const h8* __restrict__ W28,      // [l*192][384]
                    const h8* __restrict__ Wlm8,     // [48][258]
                    float* __restrict__ out,
                    _Float16* __restrict__ kbuf,
                    _Float16* __restrict__ vbuf)
{
  __shared__ float xs[2][4][BH];                     // residual stream (f32)
  __shared__ __align__(16) _Float16 xh[2][4][BH];    // residual as f16 (GEMM input)
  __shared__ __align__(16) _Float16 qh[2][4][BH];    // q (f16, pre-scaled)
  __shared__ __align__(16) _Float16 oh[2][4][BH];    // attention out (f16)
  __shared__ float sc[2][NH][4][TT];
  __shared__ __align__(16) union Scr {
    float qkvp[3][2][4][BH];                         // QKV split-K partials
    float wop[2][4][BH];                             // Wo partials
    struct { __align__(16) _Float16 f1h[2][4][4*BH]; // gelu out f16
             float w2p[2][4][BH]; } ffn;             // W2 partials
    __align__(16) _Float16 xin[2][H_IN];             // staged input x
  } scr;
  __shared__ float redsq[2][4][6];                   // x^2 wave-sums per (s,tok)
  __shared__ float redv[12];
  __shared__ int   redi[12];
  __shared__ int   fin[2];

  const int tid = threadIdx.x;
  const int kg  = tid / BH;        // split-K group (0/1); also seq index
  const int col = tid - kg * BH;   // 0..383
  const int sq  = kg;
  const int og  = 1 - kg;          // other group / other seq
  const int wid = tid >> 6;        // wave id 0..11
  const int w6  = wid % 6;
  const int seq0 = blockIdx.x * 2;

  if (tid < 2) fin[tid] = 0;

  // ---- stage x as f16 (NT: read-once) ----
  for (int s = 0; s < 2; s++) {
    const size_t base = (size_t)(seq0 + s) * H_IN;
    for (int j = tid; j < H_IN; j += NTH) scr.xin[s][j] = (_Float16)ntload(&x[base + j]);
  }
  __syncthreads();
  // ---- x0 = (x_row @ Wproj).reshape(P, BH); epilogue fuses f16 stage + x^2 sums ----
  {
    float acc[2][2] = {};
    for (int j8 = 0; j8 < H_IN / 8; j8 += 4) {
      W16 w0[4], w1[4];
      #pragma unroll
      for (int u = 0; u < 4; u++) {
        w0[u].v8 = ntload(&Wproj8[(size_t)(j8 + u) * (PP * BH) + tid]);
        w1[u].v8 = ntload(&Wproj8[(size_t)(j8 + u) * (PP * BH) + tid + NTH]);
      }
      #pragma unroll
      for (int u = 0; u < 4; u++)
        #pragma unroll
        for (int s = 0; s < 2; s++) {
          W16 hv; hv.v8 = *(const h8*)&scr.xin[s][(j8 + u) * 8];
          #pragma unroll
          for (int r = 0; r < 4; r++) {
            acc[s][0] = fdot2(hv.h[r], w0[u].h[r], acc[s][0]);
            acc[s][1] = fdot2(hv.h[r], w1[u].h[r], acc[s][1]);
          }
        }
    }
    const int m0 = tid / BH, cc = tid - m0 * BH;     // tok pair (m0, m0+2)
    #pragma unroll
    for (int s = 0; s < 2; s++) {
      xs[s][m0][cc]     = acc[s][0];  xh[s][m0][cc]     = (_Float16)acc[s][0];
      xs[s][m0 + 2][cc] = acc[s][1];  xh[s][m0 + 2][cc] = (_Float16)acc[s][1];
      float r0 = acc[s][0] * acc[s][0], r1 = acc[s][1] * acc[s][1];
      #pragma unroll
      for (int off = 32; off; off >>= 1) {
        r0 += __shfl_down(r0, off, 64); r1 += __shfl_down(r1, off, 64);
      }
      if ((tid & 63) == 0) { redsq[s][m0][w6] = r0; redsq[s][m0 + 2][w6] = r1; }
    }
  }
  __syncthreads();

  auto layers = [&](auto ntc, int pos, bool causal) {
    constexpr int NT = decltype(ntc)::value;
    const int nk = pos + NT;
    for (int l = 0; l < NL; l++) {
      // ==== q,k,v = sca * (x @ gW) (split-K; gamma folded; sca at epilogue) ====
      {
        const size_t wb = ((size_t)l * 48 + kg * 24) * BH + col;
        float aq[2][NT] = {}, ak[2][NT] = {}, av[2][NT] = {};
        for (int j8 = 0; j8 < 24; j8 += 4) {
          W16 wq[4], wk[4], wv[4];
          #pragma unroll
          for (int u = 0; u < 4; u++) {
            wq[u].v8 = Wq8[wb + (size_t)(j8 + u) * BH];
            wk[u].v8 = Wk8[wb + (size_t)(j8 + u) * BH];
            wv[u].v8 = Wv8[wb + (size_t)(j8 + u) * BH];
          }
          #pragma unroll
          for (int u = 0; u < 4; u++)
            #pragma unroll
            for (int s = 0; s < 2; s++)
              #pragma unroll
              for (int tok = 0; tok < NT; tok++) {
                W16 hv; hv.v8 = *(const h8*)&xh[s][tok][(kg * 24 + j8 + u) * 8];
                #pragma unroll
                for (int r = 0; r < 4; r++) {
                  aq[s][tok] = fdot2(hv.h[r], wq[u].h[r], aq[s][tok]);
                  ak[s][tok] = fdot2(hv.h[r], wk[u].h[r], ak[s][tok]);
                  av[s][tok] = fdot2(hv.h[r], wv[u].h[r], av[s][tok]);
                }
              }
        }
        // each group writes its OTHER-seq partials; combines its own seq
        #pragma unroll
        for (int tok = 0; tok < NT; tok++) {
          scr.qkvp[0][og][tok][col] = aq[og][tok];
          scr.qkvp[1][og][tok][col] = ak[og][tok];
          scr.qkvp[2][og][tok][col] = av[og][tok];
        }
        __syncthreads();
        {
          const size_t cb = (((size_t)(seq0 + kg) * NL + l) * TT + pos) * BH + col;
          #pragma unroll
          for (int tok = 0; tok < NT; tok++) {
            float ss = redsq[kg][tok][0] + redsq[kg][tok][1] + redsq[kg][tok][2] +
                       redsq[kg][tok][3] + redsq[kg][tok][4] + redsq[kg][tok][5];
            float sca = rsqrtf(ss * (1.0f / BH) + 1e-5f);
            qh[kg][tok][col] = (_Float16)((aq[kg][tok] + scr.qkvp[0][kg][tok][col]) * sca * RSCALE);
            ntstore(&kbuf[cb + (size_t)tok * BH],
                    (_Float16)((ak[kg][tok] + scr.qkvp[1][kg][tok][col]) * sca));
            ntstore(&vbuf[cb + (size_t)tok * BH],
                    (_Float16)((av[kg][tok] + scr.qkvp[2][kg][tok][col]) * sca));
          }
        }
        __syncthreads();
      }
      // ==== scores (RSCALE pre-folded into q; NT KV reads) ====
      {
        const int nu = 2 * NH * NT * nk;   // <= 256
        if (tid < nu) {
          int s = tid / (NH * NT * nk), r = tid % (NH * NT * nk);
          int h = r / (NT * nk); int r2 = r % (NT * nk);
          int qi = r2 / nk, j = r2 % nk;
          float d;
          if (causal && j > pos + qi) d = -1e30f;
          else {
            const h8* kp8 = (const h8*)(kbuf + (((size_t)(seq0 + s) * NL + l) * TT + j) * BH + h * HD);
            W16 kk[6];
            #pragma unroll
            for (int c = 0; c < 6; c++) kk[c].v8 = ntload(&kp8[c]);
            d = 0.f;
            #pragma unroll
            for (int c = 0; c < 6; c++)
              #pragma unroll
              for (int e = 0; e < 8; e++)
                d += (float)qh[s][qi][h * HD + c * 8 + e] * (float)kk[c].e[e];
          }
          sc[s][h][qi][j] = d;
        }
      }
      __syncthreads();
      // ==== softmax over keys ====
      {
        const int nr = 2 * NH * NT;
        if (tid < nr) {
          int s = tid / (NH * NT), r = tid % (NH * NT);
          int h = r / NT, qi = r % NT;
          float m = -3.0e38f;
          for (int j = 0; j < nk; j++) m = fmaxf(m, sc[s][h][qi][j]);
          float den = 0.f;
          for (int j = 0; j < nk; j++) {
            float e = expf(sc[s][h][qi][j] - m);
            sc[s][h][qi][j] = e; den += e;
          }
          float inv = 1.0f / den;
          for (int j = 0; j < nk; j++) sc[s][h][qi][j] *= inv;
        }
      }
      __syncthreads();
      // ==== o = p @ V (NT KV reads) ====
      {
        const size_t vb = (((size_t)(seq0 + sq) * NL + l) * TT) * BH + col;
        const int h = col / HD;
        #pragma unroll
        for (int tok = 0; tok < NT; tok++) {
          float acc = 0.f;
          int j = 0;
          for (; j + 4 <= nk; j += 4) {
            float v0 = (float)ntload(&vbuf[vb + (size_t)(j + 0) * BH]);
            float v1 = (float)ntload(&vbuf[vb + (size_t)(j + 1) * BH]);
            float v2 = (float)ntload(&vbuf[vb + (size_t)(j + 2) * BH]);
            float v3 = (float)ntload(&vbuf[vb + (size_t)(j + 3) * BH]);
            acc += sc[sq][h][tok][j] * v0 + sc[sq][h][tok][j+1] * v1 +
                   sc[sq][h][tok][j+2] * v2 + sc[sq][h][tok][j+3] * v3;
          }
          for (; j < nk; j++)
            acc += sc[sq][h][tok][j] * (float)ntload(&vbuf[vb + (size_t)j * BH]);
          oh[sq][tok][col] = (_Float16)acc;
        }
      }
      __syncthreads();
      // ==== x += o @ Wo (split-K); epilogue split by seq; fuses xh + x^2 sums ====
      {
        const size_t wb = ((size_t)l * 48 + kg * 24) * BH + col;
        float ao[2][NT] = {};
        for (int j8 = 0; j8 < 24; j8 += 8) {
          W16 w[8];
          #pragma unroll
          for (int u = 0; u < 8; u++) w[u].v8 = Wo8[wb + (size_t)(j8 + u) * BH];
          #pragma unroll
          for (int u = 0; u < 8; u++)
            #pragma unroll
            for (int s = 0; s < 2; s++)
              #pragma unroll
              for (int tok = 0; tok < NT; tok++) {
                W16 hv; hv.v8 = *(const h8*)&oh[s][tok][(kg * 24 + j8 + u) * 8];
                #pragma unroll
                for (int r = 0; r < 4; r++)
                  ao[s][tok] = fdot2(hv.h[r], w[u].h[r], ao[s][tok]);
              }
        }
        #pragma unroll
        for (int tok = 0; tok < NT; tok++) scr.wop[og][tok][col] = ao[og][tok];
        __syncthreads();
        #pragma unroll
        for (int tok = 0; tok < NT; tok++) {
          float xn = xs[kg][tok][col] + ao[kg][tok] + scr.wop[kg][tok][col];
          xs[kg][tok][col] = xn; xh[kg][tok][col] = (_Float16)xn;
          float r = xn * xn;
          #pragma unroll
          for (int off = 32; off; off >>= 1) r += __shfl_down(r, off, 64);
          if ((tid & 63) == 0) redsq[kg][tok][w6] = r;
        }
        __syncthreads();
      }
      // ==== x += gelu(sca2 * (x @ gW1)) @ W2 (gamma folded; sca2 at gelu) ====
      {
        float a1[2][NT][2] = {};
        for (int j8 = 0; j8 < 48; j8 += 4) {
          W16 w0[4], w1[4];
          #pragma unroll
          for (int u = 0; u < 4; u++) {
            w0[u].v8 = W18[((size_t)(l * 48 + j8 + u)) * (4 * BH) + tid];
            w1[u].v8 = W18[((size_t)(l * 48 + j8 + u)) * (4 * BH) + tid + NTH];
          }
          #pragma unroll
          for (int u = 0; u < 4; u++)
            #pragma unroll
            for (int s = 0; s < 2; s++)
              #pragma unroll
              for (int t = 0; t < NT; t++) {
                W16 hv; hv.v8 = *(const h8*)&xh[s][t][(j8 + u) * 8];
                #pragma unroll
                for (int r = 0; r < 4; r++) {
                  a1[s][t][0] = fdot2(hv.h[r], w0[u].h[r], a1[s][t][0]);
                  a1[s][t][1] = fdot2(hv.h[r], w1[u].h[r], a1[s][t][1]);
                }
              }
        }
        #pragma unroll
        for (int s = 0; s < 2; s++)
          #pragma unroll
          for (int t = 0; t < NT; t++) {
            float ss = redsq[s][t][0] + redsq[s][t][1] + redsq[s][t][2] +
                       redsq[s][t][3] + redsq[s][t][4] + redsq[s][t][5];
            float sca = rsqrtf(ss * (1.0f / BH) + 1e-5f);
            float z0 = a1[s][t][0] * sca, z1 = a1[s][t][1] * sca;
            scr.ffn.f1h[s][t][tid]       = (_Float16)(0.5f * z0 * (1.0f + erff(z0 * 0.7071067811865476f)));
            scr.ffn.f1h[s][t][tid + NTH] = (_Float16)(0.5f * z1 * (1.0f + erff(z1 * 0.7071067811865476f)));
          }
        __syncthreads();
        // W2: split-K; epilogue split by seq; fuses xh + x^2 sums
        {
          float a2[2][NT] = {};
          for (int j8 = 0; j8 < 96; j8 += 8) {
            W16 w[8];
            #pragma unroll
            for (int u = 0; u < 8; u++)
              w[u].v8 = W28[((size_t)(l * 192 + kg * 96 + j8 + u)) * BH + col];
            #pragma unroll
            for (int u = 0; u < 8; u++)
              #pragma unroll
              for (int s = 0; s < 2; s++)
                #pragma unroll
                for (int t = 0; t < NT; t++) {
                  W16 fv; fv.v8 = *(const h8*)&scr.ffn.f1h[s][t][(kg * 96 + j8 + u) * 8];
                  #pragma unroll
                  for (int r = 0; r < 4; r++)
                    a2[s][t] = fdot2(fv.h[r], w[u].h[r], a2[s][t]);
                }
          }
          #pragma unroll
          for (int t = 0; t < NT; t++) scr.ffn.w2p[og][t][col] = a2[og][t];
          __syncthreads();
          #pragma unroll
          for (int t = 0; t < NT; t++) {
            float xn = xs[kg][t][col] + a2[kg][t] + scr.ffn.w2p[kg][t][col];
            xs[kg][t][col] = xn; xh[kg][t][col] = (_Float16)xn;
            float r = xn * xn;
            #pragma unroll
            for (int off = 32; off; off >>= 1) r += __shfl_down(r, off, 64);
            if ((tid & 63) == 0) redsq[kg][t][w6] = r;
          }
          __syncthreads();
        }
      }
    }
  };

  for (int i = 0; i < S_CNT; i++) {
    int grow;
    if (i == 0) { layers(IC<4>{}, 0, true);           grow = 3; }
    else        { layers(IC<1>{}, PP + i - 1, false); grow = 0; }

    // ---- phase A: argmax partials + next-token copy (fused f16 stage + sums) ----
    {
      float gen = xs[sq][grow][col];
      float v = gen; int idx = col;
      #pragma unroll
      for (int off = 32; off; off >>= 1) {
        float v2 = __shfl_down(v, off, 64); int i2 = __shfl_down(idx, off, 64);
        if (v2 > v || (v2 == v && i2 < idx)) { v = v2; idx = i2; }
      }
      if ((tid & 63) == 0) { redv[wid] = v; redi[wid] = idx; }
      float nxt = fin[sq] ? 0.0f : gen;
      xs[sq][0][col] = nxt; xh[sq][0][col] = (_Float16)nxt;
      float r = nxt * nxt;
      #pragma unroll
      for (int off = 32; off; off >>= 1) r += __shfl_down(r, off, 64);
      if ((tid & 63) == 0) redsq[sq][0][w6] = r;
      __syncthreads();
    }
    // ---- phase B: argmax finalize (+fin update by same thread) + logits ----
    {
      if (col == 0) {
        const int b = sq * 6;
        float bv = redv[b]; int bi = redi[b];
        for (int w = 1; w < 6; w++)
          if (redv[b + w] > bv || (redv[b + w] == bv && redi[b + w] < bi)) {
            bv = redv[b + w]; bi = redi[b + w];
          }
        if (bi == EOS_I) fin[sq] = 1;
      }
      if (col < NV) {
        float acc = 0.f;
        for (int j8 = 0; j8 < 48; j8 += 8) {
          W16 w[8];
          #pragma unroll
          for (int u = 0; u < 8; u++) w[u].v8 = Wlm8[(size_t)(j8 + u) * NV + col];
          #pragma unroll
          for (int u = 0; u < 8; u++) {
            W16 gv; gv.v8 = *(const h8*)&xh[sq][0][(j8 + u) * 8];
            #pragma unroll
            for (int r = 0; r < 4; r++) acc = fdot2(gv.h[r], w[u].h[r], acc);
          }
        }
        ntstore(&out[((size_t)(seq0 + sq) * S_CNT + i) * NV + col], acc);
      }
      __syncthreads();
    }
  }
}

extern "C" void kernel_launch(void* const* d_in, const int* in_sizes, int n_in,
                              void* d_out, int out_size, void* d_ws, size_t ws_size,
                              hipStream_t stream) {
  const float* x     = (const float*)d_in[0];
  // d_in[1] = target (unused)
  const float* Wproj = (const float*)d_in[2];
  const float* an    = (const float*)d_in[3];
  const float* Wq    = (const float*)d_in[4];
  const float* Wk    = (const float*)d_in[5];
  const float* Wv    = (const float*)d_in[6];
  const float* Wo    = (const float*)d_in[7];
  const float* fn    = (const float*)d_in[8];
  const float* W1    = (const float*)d_in[9];
  const float* W2    = (const float*)d_in[10];
  const float* Wlm   = (const float*)d_in[11];
  float* out = (float*)d_out;
  (void)ws_size; (void)in_sizes; (void)n_in; (void)out_size;

  // ---- carve d_ws: h8-packed weights (gamma folded into Wq/Wk/Wv/W1), then f16 KV ----
  h8* w = (h8*)d_ws;
  const int n_proj = (H_IN / 8) * (PP * BH);
  const int n_qkvo = NL * (BH / 8) * BH;
  const int n_w1   = NL * (BH / 8) * (4 * BH);
  const int n_w2   = NL * (4 * BH / 8) * BH;
  const int n_lm   = (BH / 8) * NV;
  h8* Wproj_p = w;  w += n_proj;
  h8* Wq_p    = w;  w += n_qkvo;
  h8* Wk_p    = w;  w += n_qkvo;
  h8* Wv_p    = w;  w += n_qkvo;
  h8* Wo_p    = w;  w += n_qkvo;
  h8* W1_p    = w;  w += n_w1;
  h8* W2_p    = w;  w += n_w2;
  h8* Wlm_p   = w;  w += n_lm;
  const size_t kv_elems = (size_t)NSEQ * NL * TT * BH;
  _Float16* kbuf = (_Float16*)w;
  _Float16* vbuf = kbuf + kv_elems;

  auto pack = [&](const float* src, const float* g, h8* dst, int R, int C) {
    dim3 grid((C + 255) / 256, R / 8);
    pack8_kernel<<<grid, 256, 0, stream>>>(src, g, dst, C);
  };
  pack(Wproj, nullptr, Wproj_p, H_IN,        PP * BH);
  pack(Wq,    an,      Wq_p,    NL * BH,     BH);
  pack(Wk,    an,      Wk_p,    NL * BH,     BH);
  pack(Wv,    an,      Wv_p,    NL * BH,     BH);
  pack(Wo,    nullptr, Wo_p,    NL * BH,     BH);
  pack(W1,    fn,      W1_p,    NL * BH,     4 * BH);
  pack(W2,    nullptr, W2_p,    NL * 4 * BH, BH);
  pack(Wlm,   nullptr, Wlm_p,   BH,          NV);

  decoder_kernel<<<NSEQ / 2, NTH, 0, stream>>>(
      x, Wproj_p, Wq_p, Wk_p, Wv_p, Wo_p, W1_p, W2_p, Wlm_p, out, kbuf, vbuf);
}